// Round 2
// baseline (953.540 us; speedup 1.0000x reference)
//
#include <hip/hip_runtime.h>
#include <math.h>

// B,C,T = 32,1024,1024; beta=0.95; thr=1.0; sigma=10.5
#define B_   32
#define C_   1024
#define T_   1024
#define RT   92                     // f32 tap radius: dropped |d|>92 taps contribute <1e-19 abs
#define CT   64                     // channels per block
#define TT   64                     // time chunk
#define KC   16                     // channels per thread
#define ROWS (CT + 2*RT)            // 248 staged rows
#define WN   (2*(RT + KC - 1) + 1)  // 215 padded taps
#define WOFF (RT + KC - 1)          // 107 center

// Fully f32, replicating the numpy reference's op sequence and summation order:
//   w:    u=(j-i)/s; w=(1/(s*sqrt(2pi_f)))*exp((-0.5*u)*u)   (all f32 rounds; exp corr.-rounded)
//   conv: acc = fmaf(w[d], x[j], acc), j ascending            (einsum stride0*contig FMA loop)
//   I:    x - conv (one f32 sub)
//   scan: m = ((0.95f*m) + I) - r, each op rounded, no contraction;
//         r = soft + fl(1-soft) when m>1 (the f32 stop_gradient identity: r = 1 +- 1ulp noise!)
__global__ __launch_bounds__(256) void snn_fused_f32(
    const float* __restrict__ x, const float* __restrict__ sigma,
    float* __restrict__ out)
{
    __shared__ float xs[ROWS * TT];   // 63488 B; overlaid after conv reads by:
    __shared__ float wpad[WN];        //   Is [CT][65] at xs+0, sps [TT][65] at xs+CT*65
    float* Is  = xs;
    float* sps = xs + CT * 65;

    const int tx   = threadIdx.x;       // time lane 0..63
    const int ty   = threadIdx.y;       // channel group 0..3
    const int flat = ty * 64 + tx;
    const int b    = blockIdx.y;
    const int c0   = blockIdx.x * CT;

    // ---- per-block f32 tap table (numpy op order; exp via correctly-rounded f64) ----
    if (flat < WN) {
        int d = flat - WOFF;
        float w = 0.0f;
        if (d >= -RT && d <= RT) {
            float s    = sigma[0];                               // 10.5f exactly
            float u    = __fdiv_rn((float)d, s);
            float t1   = __fmul_rn(-0.5f, u);
            float t2   = __fmul_rn(t1, u);
            float e    = (float)exp((double)t2);                 // corr-rounded f32 exp
            float den  = __fmul_rn(s, sqrtf(6.2831854820251465f)); // sqrtf((f32)(2*pi))
            float coef = __fdiv_rn(1.0f, den);
            w = __fmul_rn(coef, e);
        }
        wpad[flat] = w;
    }

    const float* xb = x   + (size_t)b * ((size_t)C_ * T_);
    float*       ob = out + (size_t)b * ((size_t)C_ * T_);

    const float PI_F = 3.14159274101257324219f;  // (float)pi
    float mem = 0.0f;                             // channel c0+tx, owned by ty==0

    for (int t0 = 0; t0 < T_; t0 += TT) {
        __syncthreads();  // covers wpad init and prev-chunk sps reads

        // ---- stage x tile: channels [c0-RT, c0+CT+RT), times [t0, t0+TT) ----
        for (int e = flat; e < ROWS * TT; e += 256) {
            int r = e >> 6, col = e & 63;
            int c = c0 - RT + r;
            xs[e] = (c >= 0 && c < C_) ? xb[(size_t)c * T_ + t0 + col] : 0.0f;
        }
        __syncthreads();

        // ---- conv: sequential ascending-j f32 FMA chain per output ----
        float acc[KC];
#pragma unroll
        for (int k = 0; k < KC; ++k) acc[k] = 0.0f;

        const int rb = ty * KC;
#pragma unroll 2
        for (int jj = 0; jj < 2 * RT + KC; ++jj) {   // 200 source rows, ascending j
            float xv = xs[(rb + jj) * TT + tx];
#pragma unroll
            for (int k = 0; k < KC; ++k) {
                // d = jj - RT - k; wave-uniform wpad index -> LDS broadcast
                acc[k] = fmaf(wpad[jj + (KC - 1) - k], xv, acc[k]);
            }
        }
        float Iv[KC];
#pragma unroll
        for (int k = 0; k < KC; ++k) {
            float xo = xs[(rb + RT + k) * TT + tx];  // own x (read before overlay)
            Iv[k] = __fsub_rn(xo, acc[k]);           // I = x - conv
        }
        __syncthreads();

        // ---- write I tile (overlays xs; all xs reads complete) ----
#pragma unroll
        for (int k = 0; k < KC; ++k)
            Is[(rb + k) * 65 + tx] = Iv[k];
        __syncthreads();

        // ---- LIF scan (wave 0; lane = local channel), exact f32 op replication ----
        if (ty == 0) {
            float m = mem;
            for (int t = 0; t < TT; ++t) {
                float Ivv = Is[tx * 65 + t];
                float ur  = __fsub_rn(m, 1.0f);          // exact (Sterbenz range)
                float r;
                if (ur > 0.0f) {
                    // reference reset = soft + fl(1 - soft)  (= 1 +- ~1e-7, feeds back!)
                    float tt   = __fmul_rn(PI_F, ur);
                    float at   = (float)atan((double)tt); // corr-rounded f32 atan
                    float soft = __fdiv_rn(at, PI_F);
                    r = __fadd_rn(soft, __fsub_rn(1.0f, soft));
                } else {
                    r = 0.0f;                             // soft + (0 - soft) == 0 exactly
                }
                m = __fsub_rn(__fadd_rn(__fmul_rn(0.95f, m), Ivv), r);
                sps[t * 65 + tx] = (__fsub_rn(m, 1.0f) > 0.0f) ? 1.0f : 0.0f;
            }
            mem = m;
        }
        __syncthreads();

        // ---- coalesced spike store ----
        for (int e = flat; e < CT * TT; e += 256) {
            int r = e >> 6, col = e & 63;
            ob[(size_t)(c0 + r) * T_ + t0 + col] = sps[col * 65 + r];
        }
    }
}

extern "C" void kernel_launch(void* const* d_in, const int* in_sizes, int n_in,
                              void* d_out, int out_size, void* d_ws, size_t ws_size,
                              hipStream_t stream) {
    const float* x     = (const float*)d_in[0];   // [32,1024,1024] f32
    const float* sigma = (const float*)d_in[1];   // [1] f32
    float* out = (float*)d_out;

    dim3 grid(C_ / CT, B_);   // (16, 32)
    dim3 block(64, 4);
    snn_fused_f32<<<grid, block, 0, stream>>>(x, sigma, out);
}

// Round 3
// 278.960 us; speedup vs baseline: 3.4182x; 3.4182x over previous
//
#include <hip/hip_runtime.h>
#include <math.h>

// B,C,T = 32,1024,1024; beta=0.95; thr=1.0; sigma=10.5
#define B_   32
#define C_   1024
#define T_   1024
#define RT   92                     // tap radius: dropped |d|>92 taps < 1e-19 absolute
#define CT   64                     // channels per block
#define TT   64                     // time chunk
#define KC   16                     // channels per thread
#define ROWS (CT + 2*RT)            // 248 staged rows
#define NJJ  (2*RT + KC)            // 200 source rows per thread-group
#define WN   (2*(RT + KC - 1) + 1)  // 215 padded taps
#define WOFF (RT + KC - 1)          // 107 center

// numpy-faithful f32 tap table (identical op sequence to the reference):
//   u=(j-i)/s; w = (1/(s*sqrtf((f32)(2pi)))) * exp(-0.5*u*u), every op f32-rounded,
//   exp via correctly-rounded double. Bit-identical to the v2 kernel that passed.
__device__ __forceinline__ float tap_value(float s, int d) {
    float u    = __fdiv_rn((float)d, s);
    float t1   = __fmul_rn(-0.5f, u);
    float t2   = __fmul_rn(t1, u);
    float e    = (float)exp((double)t2);
    float den  = __fmul_rn(s, sqrtf(6.2831854820251465f));
    float coef = __fdiv_rn(1.0f, den);
    return __fmul_rn(coef, e);
}

__global__ void init_w_kernel(const float* __restrict__ sigma, float* __restrict__ gw) {
    int i = threadIdx.x;
    if (i < WN) {
        int d = i - WOFF;
        gw[i] = (d >= -RT && d <= RT) ? tap_value(sigma[0], d) : 0.0f;
    }
}

// GW=true: taps from global (wave-uniform index -> s_load / SGPR operand in the FMA).
// GW=false: fallback, taps in LDS (if ws_size too small).
template <bool GW>
__global__ __launch_bounds__(256) void snn_v3(
    const float* __restrict__ x, const float* __restrict__ sigma,
    const float* __restrict__ gw, float* __restrict__ out)
{
    __shared__ __align__(16) float xs[ROWS * TT];  // 63488 B; overlaid after conv by:
    __shared__ float wl[WN];                       //   Is [CT][65], sps [TT][65]
    float* Is  = xs;
    float* sps = xs + CT * 65;

    const int tx   = threadIdx.x;       // time lane 0..63
    const int ty   = threadIdx.y;       // channel group 0..3
    const int flat = ty * 64 + tx;
    const int b    = blockIdx.y;
    const int c0   = blockIdx.x * CT;

    if (!GW) {
        if (flat < WN) {
            int d = flat - WOFF;
            wl[flat] = (d >= -RT && d <= RT) ? tap_value(sigma[0], d) : 0.0f;
        }
    }

    const float* xb = x   + (size_t)b * ((size_t)C_ * T_);
    float*       ob = out + (size_t)b * ((size_t)C_ * T_);

    float mem = 0.0f;   // membrane of channel c0+tx, owned by ty==0 lanes

    for (int t0 = 0; t0 < T_; t0 += TT) {
        __syncthreads();  // covers wl init and prev-chunk sps reads

        // ---- stage x tile (float4): channels [c0-RT, c0+CT+RT), times [t0,t0+TT) ----
        for (int e = flat; e < ROWS * 16; e += 256) {
            int r = e >> 4, c4 = e & 15;
            int c = c0 - RT + r;
            float4 v = make_float4(0.f, 0.f, 0.f, 0.f);
            if (c >= 0 && c < C_)
                v = *(const float4*)(xb + (size_t)c * T_ + t0 + c4 * 4);
            *(float4*)(xs + r * TT + c4 * 4) = v;
        }
        __syncthreads();

        // ---- conv: sequential ascending-j f32 FMA chain per output ----
        float acc[KC];
#pragma unroll
        for (int k = 0; k < KC; ++k) acc[k] = 0.0f;

        const int rb = ty * KC;
#pragma unroll 8
        for (int jj = 0; jj < NJJ; ++jj) {           // 200 rows, ascending j
            float xv = xs[(rb + jj) * TT + tx];      // conflict-free b32 column read
#pragma unroll
            for (int k = 0; k < KC; ++k) {
                // d = jj - RT - k; index is wave-uniform -> SGPR tap when GW
                float wv = GW ? gw[jj + (KC - 1) - k] : wl[jj + (KC - 1) - k];
                acc[k] = fmaf(wv, xv, acc[k]);
            }
        }
        float Iv[KC];
#pragma unroll
        for (int k = 0; k < KC; ++k) {
            float xo = xs[(rb + RT + k) * TT + tx];  // own x (before overlay)
            Iv[k] = __fsub_rn(xo, acc[k]);           // I = x - conv
        }
        __syncthreads();

        // ---- write I tile (overlays xs; all xs reads done) ----
#pragma unroll
        for (int k = 0; k < KC; ++k)
            Is[(rb + k) * 65 + tx] = Iv[k];
        __syncthreads();

        // ---- LIF scan (wave 0, lane = local channel) ----
        // reset = RN(soft + RN(1-soft)) == 1.0f exactly for all soft in (0,0.5)
        // (|delta| <= 2^-25 = half-ulp below 1; tie rounds to even = 1.0), so the
        // reference's atan branch is bit-exactly equivalent to a compare.
        if (ty == 0) {
            float m = mem;
#pragma unroll 8
            for (int t = 0; t < TT; ++t) {
                float Ivv = Is[tx * 65 + t];
                float r   = (m > 1.0f) ? 1.0f : 0.0f;
                m = __fsub_rn(__fadd_rn(__fmul_rn(0.95f, m), Ivv), r);
                sps[t * 65 + tx] = (m > 1.0f) ? 1.0f : 0.0f;
            }
            mem = m;
        }
        __syncthreads();

        // ---- spike store (float4 along t) ----
        for (int e = flat; e < CT * 16; e += 256) {
            int r = e >> 4, c4 = e & 15;
            float4 v;
            v.x = sps[(c4 * 4 + 0) * 65 + r];
            v.y = sps[(c4 * 4 + 1) * 65 + r];
            v.z = sps[(c4 * 4 + 2) * 65 + r];
            v.w = sps[(c4 * 4 + 3) * 65 + r];
            *(float4*)(ob + (size_t)(c0 + r) * T_ + t0 + c4 * 4) = v;
        }
    }
}

extern "C" void kernel_launch(void* const* d_in, const int* in_sizes, int n_in,
                              void* d_out, int out_size, void* d_ws, size_t ws_size,
                              hipStream_t stream) {
    const float* x     = (const float*)d_in[0];   // [32,1024,1024] f32
    const float* sigma = (const float*)d_in[1];   // [1] f32
    float* out = (float*)d_out;

    dim3 grid(C_ / CT, B_);   // (16, 32) = 512 blocks
    dim3 block(64, 4);

    if (ws_size >= WN * sizeof(float)) {
        float* gw = (float*)d_ws;
        init_w_kernel<<<1, 256, 0, stream>>>(sigma, gw);
        snn_v3<true><<<grid, block, 0, stream>>>(x, sigma, gw, out);
    } else {
        snn_v3<false><<<grid, block, 0, stream>>>(x, sigma, nullptr, out);
    }
}

// Round 4
// 203.743 us; speedup vs baseline: 4.6801x; 1.3692x over previous
//
#include <hip/hip_runtime.h>
#include <math.h>

// B,C,T = 32,1024,1024; beta=0.95; thr=1.0; sigma=10.5
#define B_   32
#define C_   1024
#define T_   1024
#define RT   92                     // tap radius (|d|>92 provably cannot flip any f32 spike)
#define CT   64                     // channels per block
#define TT   64                     // time chunk
#define KC   16                     // channels per thread
#define ROWS (CT + 2*RT)            // 248 staged rows
#define NJJ  (2*RT + KC)            // 200 source rows per thread-group
#define WN   (2*(RT + KC - 1) + 1)  // 215 padded taps
#define WOFF (RT + KC - 1)          // 107 center
#define NF4  (ROWS * (TT/4))        // 3968 float4s per staged chunk
#define NSTG 16                     // ceil(NF4/256) per-thread stage registers

// numpy-faithful f32 tap (identical op sequence; exp via correctly-rounded f64).
__device__ __forceinline__ float tap_value(float s, int d) {
    float u    = __fdiv_rn((float)d, s);
    float t1   = __fmul_rn(-0.5f, u);
    float t2   = __fmul_rn(t1, u);
    float e    = (float)exp((double)t2);
    float den  = __fmul_rn(s, sqrtf(6.2831854820251465f));
    float coef = __fdiv_rn(1.0f, den);
    return __fmul_rn(coef, e);
}

__global__ void init_w_kernel(const float* __restrict__ sigma, float* __restrict__ gw) {
    int i = threadIdx.x;
    if (i < WN) {
        int d = i - WOFF;
        gw[i] = (d >= -RT && d <= RT) ? tap_value(sigma[0], d) : 0.0f;
    }
}

// GW=true: taps from global (wave-uniform index -> s_load/SGPR FMA operand).
template <bool GW>
__global__ __launch_bounds__(256) void snn_v4(
    const float* __restrict__ x, const float* __restrict__ sigma,
    const float* __restrict__ gw, float* __restrict__ out)
{
    __shared__ __align__(16) float xs[ROWS * TT];   // 63488 B staged x tile
    __shared__ float Is[CT * 65];                   // 16640 B I tile (transposed access)
    __shared__ float wl[GW ? 1 : WN];               // fallback tap table only

    const int tx   = threadIdx.x;       // time lane 0..63
    const int ty   = threadIdx.y;       // channel group 0..3
    const int flat = ty * 64 + tx;
    const int b    = blockIdx.y;
    const int c0   = blockIdx.x * CT;

    if (!GW) {
        if (flat < WN) {
            int d = flat - WOFF;
            wl[flat] = (d >= -RT && d <= RT) ? tap_value(sigma[0], d) : 0.0f;
        }
    }

    const float* xb = x   + (size_t)b * ((size_t)C_ * T_);
    float*       ob = out + (size_t)b * ((size_t)C_ * T_);

    // ---- register staging (T14): load chunk into regs early, ds_write late ----
    float4 stg[NSTG];  // statically indexed only (rule #20)

#define STAGE_LOAD(T0)                                                         \
    _Pragma("unroll")                                                          \
    for (int i = 0; i < NSTG; ++i) {                                           \
        int e = flat + i * 256;                                                \
        float4 v = make_float4(0.f, 0.f, 0.f, 0.f);                            \
        if (e < NF4) {                                                         \
            int r = e >> 4, c4v = e & 15;                                      \
            int c = c0 - RT + r;                                               \
            if (c >= 0 && c < C_)                                              \
                v = *(const float4*)(xb + (size_t)c * T_ + (T0) + c4v * 4);    \
        }                                                                      \
        stg[i] = v;                                                            \
    }

#define STAGE_WRITE()                                                          \
    _Pragma("unroll")                                                          \
    for (int i = 0; i < NSTG; ++i) {                                           \
        int e = flat + i * 256;                                                \
        if (e < NF4) *(float4*)(xs + (size_t)e * 4) = stg[i];                  \
    }

    STAGE_LOAD(0);

    float mem = 0.0f;   // membrane of channel c0+tx, owned by ty==0 lanes
    const int rb = ty * KC;

    for (int kk = 0; kk < T_ / TT; ++kk) {
        const int t0 = kk * TT;

        STAGE_WRITE();          // chunk kk into xs (vmcnt auto-inserted)
        __syncthreads();        // xs ready; also orders vs prev scan's Is reads

        if (kk < T_ / TT - 1) { STAGE_LOAD(t0 + TT); }  // in flight under conv

        // ---- conv: sequential ascending-j f32 FMA chain per output ----
        float acc[KC];
#pragma unroll
        for (int k = 0; k < KC; ++k) acc[k] = 0.0f;

#pragma unroll 8
        for (int jj = 0; jj < NJJ; ++jj) {           // 200 rows, ascending j
            float xv = xs[(rb + jj) * TT + tx];
#pragma unroll
            for (int k = 0; k < KC; ++k) {
                // d = jj - RT - k; wave-uniform tap index -> SGPR operand
                float wv = GW ? gw[jj + (KC - 1) - k] : wl[jj + (KC - 1) - k];
                acc[k] = fmaf(wv, xv, acc[k]);
            }
        }
        // I = x - conv, written transposed-access-friendly
#pragma unroll
        for (int k = 0; k < KC; ++k) {
            float xo = xs[(rb + RT + k) * TT + tx];
            Is[(rb + k) * 65 + tx] = __fsub_rn(xo, acc[k]);
        }
        __syncthreads();        // Is ready; all xs reads done (next stage_write safe)

        // ---- LIF scan (wave 0, lane = channel); spikes packed in regs ----
        // reset = RN(soft + RN(1-soft)) == 1.0f exactly for soft in (0,0.5),
        // so the reference's atan surrogate is bit-exactly a compare.
        if (ty == 0) {
            float m = mem;
            float* orow = ob + (size_t)(c0 + tx) * T_ + t0;
#pragma unroll
            for (int tq = 0; tq < TT / 4; ++tq) {
                float4 s;
#pragma unroll
                for (int q = 0; q < 4; ++q) {
                    float Ivv = Is[tx * 65 + tq * 4 + q];
                    float r   = (m > 1.0f) ? 1.0f : 0.0f;
                    m = __fsub_rn(__fadd_rn(__fmul_rn(0.95f, m), Ivv), r);
                    float sp  = (m > 1.0f) ? 1.0f : 0.0f;
                    if (q == 0) s.x = sp; else if (q == 1) s.y = sp;
                    else if (q == 2) s.z = sp; else s.w = sp;
                }
                *(float4*)(orow + tq * 4) = s;   // 16B/lane, lane-contiguous rows
            }
            mem = m;
        }
        __syncthreads();        // wave0 done with Is before next I-write
    }
#undef STAGE_LOAD
#undef STAGE_WRITE
}

extern "C" void kernel_launch(void* const* d_in, const int* in_sizes, int n_in,
                              void* d_out, int out_size, void* d_ws, size_t ws_size,
                              hipStream_t stream) {
    const float* x     = (const float*)d_in[0];   // [32,1024,1024] f32
    const float* sigma = (const float*)d_in[1];   // [1] f32
    float* out = (float*)d_out;

    dim3 grid(C_ / CT, B_);   // (16, 32) = 512 blocks
    dim3 block(64, 4);

    if (ws_size >= WN * sizeof(float)) {
        float* gw = (float*)d_ws;
        init_w_kernel<<<1, 256, 0, stream>>>(sigma, gw);
        snn_v4<true><<<grid, block, 0, stream>>>(x, sigma, gw, out);
    } else {
        snn_v4<false><<<grid, block, 0, stream>>>(x, sigma, nullptr, out);
    }
}

// Round 5
// 181.878 us; speedup vs baseline: 5.2428x; 1.1202x over previous
//
#include <hip/hip_runtime.h>
#include <math.h>

// B,C,T = 32,1024,1024; beta=0.95; thr=1.0; sigma=10.5
#define B_   32
#define C_   1024
#define T_   1024
#define RT   92                     // tap radius (|d|>92 provably cannot flip any f32 spike)
#define CT   64                     // channels per block
#define TT   64                     // time chunk
#define KC   8                      // channels per thread (8 ty groups * 8 = 64)
#define NTY  (CT/KC)                // 8 -> 512-thread blocks, 4 waves/SIMD
#define ROWS (CT + 2*RT)            // 248 staged rows
#define NJJ  (2*RT + KC)            // 192 source rows per thread-group (192 FMA/output)
#define WN   (2*(RT + KC - 1) + 1)  // 199 padded taps
#define WOFF (RT + KC - 1)          // 99 center
#define NF4  (ROWS * (TT/4))        // 3968 float4s per staged chunk
#define NSTG 8                      // ceil(NF4/512) per-thread stage registers

// numpy-faithful f32 tap (identical op sequence; exp via correctly-rounded f64).
__device__ __forceinline__ float tap_value(float s, int d) {
    float u    = __fdiv_rn((float)d, s);
    float t1   = __fmul_rn(-0.5f, u);
    float t2   = __fmul_rn(t1, u);
    float e    = (float)exp((double)t2);
    float den  = __fmul_rn(s, sqrtf(6.2831854820251465f));
    float coef = __fdiv_rn(1.0f, den);
    return __fmul_rn(coef, e);
}

__global__ void init_w_kernel(const float* __restrict__ sigma, float* __restrict__ gw) {
    int i = threadIdx.x;
    if (i < WN) {
        int d = i - WOFF;
        gw[i] = (d >= -RT && d <= RT) ? tap_value(sigma[0], d) : 0.0f;
    }
}

// GW=true: taps from global (wave-uniform index -> s_load/SGPR FMA operand).
template <bool GW>
__global__ __launch_bounds__(512, 4) void snn_v5(
    const float* __restrict__ x, const float* __restrict__ sigma,
    const float* __restrict__ gw, float* __restrict__ out)
{
    __shared__ __align__(16) float xs[ROWS * TT];   // 63488 B staged x tile
    __shared__ float Is[CT * 65];                   // 16640 B I tile
    __shared__ float wl[GW ? 1 : WN];               // fallback tap table only

    const int tx   = threadIdx.x;       // time lane 0..63
    const int ty   = threadIdx.y;       // channel group 0..7
    const int flat = ty * 64 + tx;
    const int b    = blockIdx.y;
    const int c0   = blockIdx.x * CT;

    if (!GW) {
        if (flat < WN) {
            int d = flat - WOFF;
            wl[flat] = (d >= -RT && d <= RT) ? tap_value(sigma[0], d) : 0.0f;
        }
    }

    const float* xb = x   + (size_t)b * ((size_t)C_ * T_);
    float*       ob = out + (size_t)b * ((size_t)C_ * T_);

    // ---- register staging (T14): load chunk into regs early, ds_write late ----
    float4 stg[NSTG];  // statically indexed only (rule #20)

#define STAGE_LOAD(T0)                                                         \
    _Pragma("unroll")                                                          \
    for (int i = 0; i < NSTG; ++i) {                                           \
        int e = flat + i * 512;                                                \
        float4 v = make_float4(0.f, 0.f, 0.f, 0.f);                            \
        if (e < NF4) {                                                         \
            int r = e >> 4, c4v = e & 15;                                      \
            int c = c0 - RT + r;                                               \
            if (c >= 0 && c < C_)                                              \
                v = *(const float4*)(xb + (size_t)c * T_ + (T0) + c4v * 4);    \
        }                                                                      \
        stg[i] = v;                                                            \
    }

#define STAGE_WRITE()                                                          \
    _Pragma("unroll")                                                          \
    for (int i = 0; i < NSTG; ++i) {                                           \
        int e = flat + i * 512;                                                \
        if (e < NF4) *(float4*)(xs + (size_t)e * 4) = stg[i];                  \
    }

    STAGE_LOAD(0);

    float mem = 0.0f;   // membrane of channel c0 + flat, owned by flat<64 lanes
    const int rb = ty * KC;

    for (int kk = 0; kk < T_ / TT; ++kk) {
        const int t0 = kk * TT;

        STAGE_WRITE();          // chunk kk into xs
        __syncthreads();        // xs ready; also orders prev scan's Is reads vs I-write

        if (kk < T_ / TT - 1) { STAGE_LOAD(t0 + TT); }  // in flight under conv

        // ---- conv: sequential ascending-j f32 FMA chain per output ----
        float acc[KC];
#pragma unroll
        for (int k = 0; k < KC; ++k) acc[k] = 0.0f;

#pragma unroll 8
        for (int jj = 0; jj < NJJ; ++jj) {           // 192 rows, ascending j
            float xv = xs[(rb + jj) * TT + tx];
#pragma unroll
            for (int k = 0; k < KC; ++k) {
                // d = jj - RT - k; wave-uniform tap index -> SGPR operand
                float wv = GW ? gw[jj + (KC - 1) - k] : wl[jj + (KC - 1) - k];
                acc[k] = fmaf(wv, xv, acc[k]);
            }
        }
        // I = x - conv
#pragma unroll
        for (int k = 0; k < KC; ++k) {
            float xo = xs[(rb + RT + k) * TT + tx];
            Is[(rb + k) * 65 + tx] = __fsub_rn(xo, acc[k]);
        }
        __syncthreads();        // Is ready; all xs reads done (next stage_write safe)

        // ---- LIF scan (wave 0; lane = local channel); spikes packed in regs ----
        // reset = RN(soft + RN(1-soft)) == 1.0f exactly for soft in (0,0.5),
        // so the reference's atan surrogate is bit-exactly a compare.
        if (flat < 64) {
            float m = mem;
            float* orow = ob + (size_t)(c0 + flat) * T_ + t0;
#pragma unroll
            for (int tq = 0; tq < TT / 4; ++tq) {
                float4 s;
#pragma unroll
                for (int q = 0; q < 4; ++q) {
                    float Ivv = Is[flat * 65 + tq * 4 + q];
                    float r   = (m > 1.0f) ? 1.0f : 0.0f;
                    m = __fsub_rn(__fadd_rn(__fmul_rn(0.95f, m), Ivv), r);
                    float sp  = (m > 1.0f) ? 1.0f : 0.0f;
                    if (q == 0) s.x = sp; else if (q == 1) s.y = sp;
                    else if (q == 2) s.z = sp; else s.w = sp;
                }
                *(float4*)(orow + tq * 4) = s;   // 16B/lane, lane-contiguous rows
            }
            mem = m;
        }
        __syncthreads();        // scan's Is reads done before next iter's I-write
    }
#undef STAGE_LOAD
#undef STAGE_WRITE
}

extern "C" void kernel_launch(void* const* d_in, const int* in_sizes, int n_in,
                              void* d_out, int out_size, void* d_ws, size_t ws_size,
                              hipStream_t stream) {
    const float* x     = (const float*)d_in[0];   // [32,1024,1024] f32
    const float* sigma = (const float*)d_in[1];   // [1] f32
    float* out = (float*)d_out;

    dim3 grid(C_ / CT, B_);   // (16, 32) = 512 blocks
    dim3 block(64, NTY);      // 512 threads, 8 waves

    if (ws_size >= WN * sizeof(float)) {
        float* gw = (float*)d_ws;
        init_w_kernel<<<1, 256, 0, stream>>>(sigma, gw);
        snn_v5<true><<<grid, block, 0, stream>>>(x, sigma, gw, out);
    } else {
        snn_v5<false><<<grid, block, 0, stream>>>(x, sigma, nullptr, out);
    }
}